// Round 12
// baseline (793.724 us; speedup 1.0000x reference)
//
#include <hip/hip_runtime.h>
#include <hip/hip_bf16.h>
#include <cstdint>

#define DD 8192
#define NROW 200
#define MT 13          // 13 M-tiles of 16 rows = 208
#define MPAD 208
#define KPV 256        // padded K for the PV GEMM
#define EPSV 1e-5f
#define BK 64

using short8 = __attribute__((ext_vector_type(8))) short;
using f32x4  = __attribute__((ext_vector_type(4))) float;

__device__ __forceinline__ ushort f2bf(float f) {
    union { float f; unsigned u; } c; c.f = f;
    unsigned u = c.u;
    return (ushort)((u + 0x7FFFu + ((u >> 16) & 1u)) >> 16);  // RNE
}

__device__ __forceinline__ short8 pack8(float4 a, float4 b) {
    short8 o;
    o[0]=f2bf(a.x); o[1]=f2bf(a.y); o[2]=f2bf(a.z); o[3]=f2bf(a.w);
    o[4]=f2bf(b.x); o[5]=f2bf(b.y); o[6]=f2bf(b.z); o[7]=f2bf(b.w);
    return o;
}

// fast pack via v_cvt_pk_bf16_f32 (RNE, same semantics as f2bf)
__device__ __forceinline__ short8 pack8f(f32x4 a, f32x4 b) {
    short8 o;
    union { __hip_bfloat162 h; unsigned u; } q;
    q.h = __float22bfloat162_rn(float2{a[0], a[1]}); o[0]=(short)(q.u & 0xffff); o[1]=(short)(q.u >> 16);
    q.h = __float22bfloat162_rn(float2{a[2], a[3]}); o[2]=(short)(q.u & 0xffff); o[3]=(short)(q.u >> 16);
    q.h = __float22bfloat162_rn(float2{b[0], b[1]}); o[4]=(short)(q.u & 0xffff); o[5]=(short)(q.u >> 16);
    q.h = __float22bfloat162_rn(float2{b[2], b[3]}); o[6]=(short)(q.u & 0xffff); o[7]=(short)(q.u >> 16);
    return o;
}

// ---------------- kernel 1: x (f32 [200][8192]) -> xb (bf16 [208][8192], pad rows 0)
__global__ void cvt_x(const float* __restrict__ x, ushort* __restrict__ xb) {
    int i = (blockIdx.x * 256 + threadIdx.x) * 8;
    int row = i >> 13;
    int col = i & (DD - 1);
    short8 o;
    if (row < NROW) {
        const float4* p = reinterpret_cast<const float4*>(x + (size_t)row * DD + col);
        float4 a = p[0], b = p[1];
        o = pack8(a, b);
    } else {
        for (int j = 0; j < 8; ++j) o[j] = 0;
    }
    *reinterpret_cast<short8*>(xb + i) = o;
}

// asm load + waits (rule 18: sched_barrier after every hand waitcnt)
#define GL(dst, ptr, OFF) \
    asm volatile("global_load_dwordx4 %0, %1, off offset:" #OFF \
                 : "=&v"(dst) : "v"(ptr) : "memory")
#define WAITV(N) asm volatile("s_waitcnt vmcnt(" #N ")" ::: "memory")
#define SB __builtin_amdgcn_sched_barrier(0)

// ---------------- kernel 2: fused QKV GEMM — FREE-RUNNING waves, no LDS, no barriers.
// grid 768 = 3 mats x 256 colblocks, block 256 (4 independent waves, M-split 4).
// Wave: 2 col-groups (32 cols) x 4 M-tiles (wave, +4, +8, +12; waves 1-3 duplicate
// tile 12 dead for uniform counts) x full K. All loads via inline-asm dwordx4 with
// hand-counted vmcnt: W(t) retired at phase t top (1-phase slack), A(t) retired
// before MFMA (1-phase slack). Steady queue: [W(t):8, A(t):8]. 12 waves/CU.
__global__ __launch_bounds__(256, 3) void qkv_fr(
    const ushort* __restrict__ xb,
    const float* __restrict__ Wq, const float* __restrict__ Wk, const float* __restrict__ Wv,
    const float* __restrict__ bq, const float* __restrict__ bk, const float* __restrict__ bv,
    ushort* __restrict__ qb, ushort* __restrict__ kb, ushort* __restrict__ vt)
{
    const int bid = blockIdx.x;
    const int mat = bid >> 8;
    const int cb  = bid & 255;
    const float* W    = (mat == 0) ? Wq : (mat == 1 ? Wk : Wv);
    const float* bias = (mat == 0) ? bq : (mat == 1 ? bk : bv);

    const int t    = threadIdx.x;
    const int lane = t & 63;
    const int wave = t >> 6;
    const int c    = lane & 15;
    const int kgrp = lane >> 4;
    const int ncol0 = cb * 32 + c;
    const int ncol1 = ncol0 + 16;

    const float* wp0 = W + (size_t)ncol0 * DD + kgrp * 8;
    const float* wp1 = W + (size_t)ncol1 * DD + kgrp * 8;

    const int mt0 = wave, mt1 = wave + 4, mt2 = wave + 8, mt3 = wave + 12;
    const int r3  = (mt3 < MT) ? mt3 : 12;     // waves 1-3: dead duplicate of tile 12
    const ushort* a0p = xb + (size_t)(mt0 * 16 + c) * DD + kgrp * 8;
    const ushort* a1p = xb + (size_t)(mt1 * 16 + c) * DD + kgrp * 8;
    const ushort* a2p = xb + (size_t)(mt2 * 16 + c) * DD + kgrp * 8;
    const ushort* a3p = xb + (size_t)(r3  * 16 + c) * DD + kgrp * 8;

    f32x4 acc00, acc01, acc10, acc11, acc20, acc21, acc30, acc31;
    for (int r = 0; r < 4; ++r) {
        acc00[r]=0.f; acc01[r]=0.f; acc10[r]=0.f; acc11[r]=0.f;
        acc20[r]=0.f; acc21[r]=0.f; acc30[r]=0.f; acc31[r]=0.f;
    }

    short8 e0,e1,e2,e3,e4,e5,e6,e7;   // A set E (tile j: e(2j)=chunk0, e(2j+1)=chunk1)
    short8 o0,o1,o2,o3,o4,o5,o6,o7;   // A set O
    f32x4 u0,u1,u2,u3,u4,u5,u6,u7;    // W fp32: col0 {0,16,128,144}, col1 {...}

#define ISSUEW { \
        GL(u0, wp0, 0); GL(u1, wp0, 16); GL(u2, wp0, 128); GL(u3, wp0, 144); \
        GL(u4, wp1, 0); GL(u5, wp1, 16); GL(u6, wp1, 128); GL(u7, wp1, 144); \
        wp0 += 64; wp1 += 64; }
#define ISSUEA(S) { \
        GL(S##0, a0p, 0); GL(S##1, a0p, 64); \
        GL(S##2, a1p, 0); GL(S##3, a1p, 64); \
        GL(S##4, a2p, 0); GL(S##5, a2p, 64); \
        GL(S##6, a3p, 0); GL(S##7, a3p, 64); \
        a0p += 64; a1p += 64; a2p += 64; a3p += 64; }
#define MF(AU) { \
        acc00 = __builtin_amdgcn_mfma_f32_16x16x32_bf16(AU##0, b00, acc00, 0, 0, 0); \
        acc01 = __builtin_amdgcn_mfma_f32_16x16x32_bf16(AU##0, b10, acc01, 0, 0, 0); \
        acc00 = __builtin_amdgcn_mfma_f32_16x16x32_bf16(AU##1, b01, acc00, 0, 0, 0); \
        acc01 = __builtin_amdgcn_mfma_f32_16x16x32_bf16(AU##1, b11, acc01, 0, 0, 0); \
        acc10 = __builtin_amdgcn_mfma_f32_16x16x32_bf16(AU##2, b00, acc10, 0, 0, 0); \
        acc11 = __builtin_amdgcn_mfma_f32_16x16x32_bf16(AU##2, b10, acc11, 0, 0, 0); \
        acc10 = __builtin_amdgcn_mfma_f32_16x16x32_bf16(AU##3, b01, acc10, 0, 0, 0); \
        acc11 = __builtin_amdgcn_mfma_f32_16x16x32_bf16(AU##3, b11, acc11, 0, 0, 0); \
        acc20 = __builtin_amdgcn_mfma_f32_16x16x32_bf16(AU##4, b00, acc20, 0, 0, 0); \
        acc21 = __builtin_amdgcn_mfma_f32_16x16x32_bf16(AU##4, b10, acc21, 0, 0, 0); \
        acc20 = __builtin_amdgcn_mfma_f32_16x16x32_bf16(AU##5, b01, acc20, 0, 0, 0); \
        acc21 = __builtin_amdgcn_mfma_f32_16x16x32_bf16(AU##5, b11, acc21, 0, 0, 0); \
        acc30 = __builtin_amdgcn_mfma_f32_16x16x32_bf16(AU##6, b00, acc30, 0, 0, 0); \
        acc31 = __builtin_amdgcn_mfma_f32_16x16x32_bf16(AU##6, b10, acc31, 0, 0, 0); \
        acc30 = __builtin_amdgcn_mfma_f32_16x16x32_bf16(AU##7, b01, acc30, 0, 0, 0); \
        acc31 = __builtin_amdgcn_mfma_f32_16x16x32_bf16(AU##7, b11, acc31, 0, 0, 0); }
#define PHASE(AU, AO) { \
        WAITV(8); SB; \
        short8 b00 = pack8f(u0, u1), b01 = pack8f(u2, u3); \
        short8 b10 = pack8f(u4, u5), b11 = pack8f(u6, u7); \
        SB; \
        ISSUEW; ISSUEA(AO); SB; \
        WAITV(16); SB; \
        MF(AU); SB; }
#define PHASEF(AU) { \
        WAITV(8); SB; \
        short8 b00 = pack8f(u0, u1), b01 = pack8f(u2, u3); \
        short8 b10 = pack8f(u4, u5), b11 = pack8f(u6, u7); \
        SB; \
        WAITV(0); SB; \
        MF(AU); SB; }

    // prologue: queue = [W(0):8, A(0):8]; ptrs -> k=64
    ISSUEW; ISSUEA(e); SB;

    #pragma unroll 1
    for (int it = 0; it < 63; ++it) {   // phases 0..125
        PHASE(e, o);
        PHASE(o, e);
    }
    PHASE(e, o);                         // phase 126 (issues k=8128 -> o)
    PHASEF(o);                           // phase 127 (no issue)

#undef PHASE
#undef PHASEF
#undef MF
#undef ISSUEA
#undef ISSUEW

    // ---------------- epilogue: direct stores (no partials)
    const float b0v = bias[ncol0];
    const float b1v = bias[ncol1];
#define STORE_TILE(MTV, A0, A1) { \
        if ((MTV) < MT) { \
            if (mat < 2) { \
                ushort* outb = (mat == 0) ? qb : kb; \
                _Pragma("unroll") for (int r = 0; r < 4; ++r) { \
                    int row = (MTV) * 16 + kgrp * 4 + r; \
                    outb[(size_t)row * DD + ncol0] = f2bf(A0[r] + b0v); \
                    outb[(size_t)row * DD + ncol1] = f2bf(A1[r] + b1v); \
                } \
            } else { \
                _Pragma("unroll") for (int r = 0; r < 4; ++r) { \
                    int row = (MTV) * 16 + kgrp * 4 + r; \
                    vt[(size_t)ncol0 * KPV + row] = f2bf(A0[r] + b0v); \
                    vt[(size_t)ncol1 * KPV + row] = f2bf(A1[r] + b1v); \
                } \
            } \
        } }
    STORE_TILE(mt0, acc00, acc01);
    STORE_TILE(mt1, acc10, acc11);
    STORE_TILE(mt2, acc20, acc21);
    STORE_TILE(mt3, acc30, acc31);
#undef STORE_TILE
}

// ---------------- kernel 4: s = q @ k^T  (f32 [208][208]); grid (13,13), 4-wave K-split
__global__ __launch_bounds__(256) void sgemm(const ushort* __restrict__ qb, const ushort* __restrict__ kb,
                                             float* __restrict__ sbuf) {
    const int bm = blockIdx.y, bn = blockIdx.x;
    const int lane  = threadIdx.x & 63;
    const int wave  = threadIdx.x >> 6;
    const int col16 = lane & 15, kgrp = lane >> 4;
    const ushort* ap = qb + (size_t)(bm * 16 + col16) * DD + kgrp * 8;
    const ushort* bp = kb + (size_t)(bn * 16 + col16) * DD + kgrp * 8;
    f32x4 acc;
    for (int r = 0; r < 4; ++r) acc[r] = 0.f;
    const int kend = (wave + 1) * 2048;
    for (int k0 = wave * 2048; k0 < kend; k0 += 32) {
        short8 a = *reinterpret_cast<const short8*>(ap + k0);
        short8 b = *reinterpret_cast<const short8*>(bp + k0);
        acc = __builtin_amdgcn_mfma_f32_16x16x32_bf16(a, b, acc, 0, 0, 0);
    }
    __shared__ f32x4 red[4][64];
    red[wave][lane] = acc;
    __syncthreads();
    if (wave == 0) {
        f32x4 s = red[0][lane];
        for (int j = 1; j < 4; ++j) { f32x4 o = red[j][lane]; for (int r = 0; r < 4; ++r) s[r] += o[r]; }
        for (int r = 0; r < 4; ++r)
            sbuf[(size_t)(bm * 16 + kgrp * 4 + r) * MPAD + bn * 16 + col16] = s[r];
    }
}

// ---------------- kernel 5: per-row mean/var(ddof=1) -> sin -> softmax -> P bf16 [208][256] (pads 0)
__global__ __launch_bounds__(256) void rownorm(const float* __restrict__ sbuf, ushort* __restrict__ pb) {
    const int row = blockIdx.x;
    const int t = threadIdx.x;
    if (row >= NROW) { pb[(size_t)row * KPV + t] = 0; return; }
    __shared__ float part[4];
    const int lane = t & 63, wave = t >> 6;
    float x = (t < NROW) ? sbuf[(size_t)row * MPAD + t] : 0.f;

    float s = x;
    for (int m = 32; m; m >>= 1) s += __shfl_xor(s, m, 64);
    if (lane == 0) part[wave] = s;
    __syncthreads();
    float mean = (part[0] + part[1] + part[2] + part[3]) * (1.f / 200.f);

    float d = (t < NROW) ? (x - mean) : 0.f;
    float s2 = d * d;
    for (int m = 32; m; m >>= 1) s2 += __shfl_xor(s2, m, 64);
    __syncthreads();
    if (lane == 0) part[wave] = s2;
    __syncthreads();
    float var = (part[0] + part[1] + part[2] + part[3]) * (1.f / 199.f);

    float inv = 1.f / sqrtf(var + EPSV);
    float y = sinf(d * inv);
    const float inv_cc = 1.f / 90.50966799187809f;   // 1/sqrt(8192)
    float e = (t < NROW) ? expf(y * inv_cc) : 0.f;

    float se = e;
    for (int m = 32; m; m >>= 1) se += __shfl_xor(se, m, 64);
    __syncthreads();
    if (lane == 0) part[wave] = se;
    __syncthreads();
    float tot = part[0] + part[1] + part[2] + part[3];
    pb[(size_t)row * KPV + t] = (t < NROW) ? f2bf(e / tot) : (ushort)0;
}

// ---------------- kernel 6: out = P @ V  via out[m][n] = sum_k P[m][k] * vt[n][k]
__global__ __launch_bounds__(256) void pv_gemm(const ushort* __restrict__ pb, const ushort* __restrict__ vt,
                                               float* __restrict__ out) {
    const int lane  = threadIdx.x & 63;
    const int wave  = threadIdx.x >> 6;
    const int col16 = lane & 15, kgrp = lane >> 4;
    const int ncol  = blockIdx.x * 64 + wave * 16 + col16;
    const ushort* ap = pb + (size_t)col16 * KPV + kgrp * 8;
    const ushort* bp = vt + (size_t)ncol  * KPV + kgrp * 8;
    f32x4 acc[MT];
    for (int m = 0; m < MT; ++m)
        for (int r = 0; r < 4; ++r) acc[m][r] = 0.f;
    for (int k0 = 0; k0 < KPV; k0 += 32) {
        short8 b = *reinterpret_cast<const short8*>(bp + k0);
        #pragma unroll
        for (int m = 0; m < MT; ++m) {
            short8 a = *reinterpret_cast<const short8*>(ap + (size_t)m * 16 * KPV + k0);
            acc[m] = __builtin_amdgcn_mfma_f32_16x16x32_bf16(a, b, acc[m], 0, 0, 0);
        }
    }
    for (int m = 0; m < MT; ++m)
        for (int r = 0; r < 4; ++r) {
            int row = m * 16 + kgrp * 4 + r;
            if (row < NROW) out[(size_t)row * DD + ncol] = acc[m][r];
        }
}

extern "C" void kernel_launch(void* const* d_in, const int* in_sizes, int n_in,
                              void* d_out, int out_size, void* d_ws, size_t ws_size,
                              hipStream_t stream) {
    const float* x  = (const float*)d_in[0];
    const float* Wq = (const float*)d_in[1];
    const float* bq = (const float*)d_in[2];
    const float* Wk = (const float*)d_in[3];
    const float* bk = (const float*)d_in[4];
    const float* Wv = (const float*)d_in[5];
    const float* bv = (const float*)d_in[6];
    float* out = (float*)d_out;

    char* ws = (char*)d_ws;
    ushort* xb   = (ushort*)(ws);                       // 208*8192*2 = 3,407,872
    ushort* qb   = (ushort*)(ws + 3407872);             // 3,407,872
    ushort* kb   = (ushort*)(ws + 6815744);             // 3,407,872
    ushort* vt   = (ushort*)(ws + 10223616);            // 8192*256*2 = 4,194,304
    float*  sbuf = (float*)(ws + 14417920);             // 208*208*4 = 173,056
    ushort* pb   = (ushort*)(ws + 14590976);            // 208*256*2 = 106,496
    // total 14,697,472 bytes

    cvt_x<<<832, 256, 0, stream>>>(x, xb);
    qkv_fr<<<768, 256, 0, stream>>>(xb, Wq, Wk, Wv, bq, bk, bv, qb, kb, vt);
    sgemm<<<dim3(13, 13), 256, 0, stream>>>(qb, kb, sbuf);
    rownorm<<<208, 256, 0, stream>>>(sbuf, pb);
    pv_gemm<<<128, 256, 0, stream>>>(pb, vt, out);
}

// Round 13
// 792.082 us; speedup vs baseline: 1.0021x; 1.0021x over previous
//
#include <hip/hip_runtime.h>
#include <hip/hip_bf16.h>
#include <cstdint>

#define DD 8192
#define NROW 200
#define MT 13          // 13 M-tiles of 16 rows = 208
#define MPAD 208
#define KPV 256        // padded K for the PV GEMM
#define EPSV 1e-5f
#define BK 64

using short8 = __attribute__((ext_vector_type(8))) short;
using f32x4  = __attribute__((ext_vector_type(4))) float;

__device__ __forceinline__ ushort f2bf(float f) {
    union { float f; unsigned u; } c; c.f = f;
    unsigned u = c.u;
    return (ushort)((u + 0x7FFFu + ((u >> 16) & 1u)) >> 16);  // RNE
}

__device__ __forceinline__ short8 pack8(float4 a, float4 b) {
    short8 o;
    o[0]=f2bf(a.x); o[1]=f2bf(a.y); o[2]=f2bf(a.z); o[3]=f2bf(a.w);
    o[4]=f2bf(b.x); o[5]=f2bf(b.y); o[6]=f2bf(b.z); o[7]=f2bf(b.w);
    return o;
}

// fast pack via v_cvt_pk_bf16_f32 (RNE, same semantics as f2bf)
__device__ __forceinline__ short8 pack8f(f32x4 a, f32x4 b) {
    short8 o;
    union { __hip_bfloat162 h; unsigned u; } q;
    q.h = __float22bfloat162_rn(float2{a[0], a[1]}); o[0]=(short)(q.u & 0xffff); o[1]=(short)(q.u >> 16);
    q.h = __float22bfloat162_rn(float2{a[2], a[3]}); o[2]=(short)(q.u & 0xffff); o[3]=(short)(q.u >> 16);
    q.h = __float22bfloat162_rn(float2{b[0], b[1]}); o[4]=(short)(q.u & 0xffff); o[5]=(short)(q.u >> 16);
    q.h = __float22bfloat162_rn(float2{b[2], b[3]}); o[6]=(short)(q.u & 0xffff); o[7]=(short)(q.u >> 16);
    return o;
}

// ---------------- kernel 1: x (f32 [200][8192]) -> xb (bf16 [208][8192], pad rows 0)
__global__ void cvt_x(const float* __restrict__ x, ushort* __restrict__ xb) {
    int i = (blockIdx.x * 256 + threadIdx.x) * 8;
    int row = i >> 13;
    int col = i & (DD - 1);
    short8 o;
    if (row < NROW) {
        const float4* p = reinterpret_cast<const float4*>(x + (size_t)row * DD + col);
        float4 a = p[0], b = p[1];
        o = pack8(a, b);
    } else {
        for (int j = 0; j < 8; ++j) o[j] = 0;
    }
    *reinterpret_cast<short8*>(xb + i) = o;
}

// asm load + waits (rule 18: sched_barrier after every hand waitcnt)
#define GL(dst, ptr, OFF) \
    asm volatile("global_load_dwordx4 %0, %1, off offset:" #OFF \
                 : "=&v"(dst) : "v"(ptr) : "memory")
#define WAITV(N) asm volatile("s_waitcnt vmcnt(" #N ")" ::: "memory")
#define SB __builtin_amdgcn_sched_barrier(0)

// ---------------- kernel 2: fused QKV GEMM — FREE-RUNNING waves, no LDS, no barriers.
// grid 768 = 3 mats x 256 colblocks, block 256 (4 independent waves, M-split 4).
// Wave: 2 col-groups (32 cols) x 4 M-tiles (wave, +4, +8, +12; waves 1-3 duplicate
// tile 12 dead for uniform counts) x full K. All loads via inline-asm dwordx4 with
// hand-counted vmcnt: W(t) retired at phase t top (1-phase slack), A(t) retired
// before MFMA (1-phase slack). Steady queue: [W(t):8, A(t):8]. 12 waves/CU.
__global__ __launch_bounds__(256, 3) void qkv_fr(
    const ushort* __restrict__ xb,
    const float* __restrict__ Wq, const float* __restrict__ Wk, const float* __restrict__ Wv,
    const float* __restrict__ bq, const float* __restrict__ bk, const float* __restrict__ bv,
    ushort* __restrict__ qb, ushort* __restrict__ kb, ushort* __restrict__ vt)
{
    const int bid = blockIdx.x;
    const int mat = bid >> 8;
    const int cb  = bid & 255;
    const float* W    = (mat == 0) ? Wq : (mat == 1 ? Wk : Wv);
    const float* bias = (mat == 0) ? bq : (mat == 1 ? bk : bv);

    const int t    = threadIdx.x;
    const int lane = t & 63;
    const int wave = t >> 6;
    const int c    = lane & 15;
    const int kgrp = lane >> 4;
    const int ncol0 = cb * 32 + c;
    const int ncol1 = ncol0 + 16;

    const float* wp0 = W + (size_t)ncol0 * DD + kgrp * 8;
    const float* wp1 = W + (size_t)ncol1 * DD + kgrp * 8;

    const int mt0 = wave, mt1 = wave + 4, mt2 = wave + 8, mt3 = wave + 12;
    const int r3  = (mt3 < MT) ? mt3 : 12;     // waves 1-3: dead duplicate of tile 12
    const ushort* a0p = xb + (size_t)(mt0 * 16 + c) * DD + kgrp * 8;
    const ushort* a1p = xb + (size_t)(mt1 * 16 + c) * DD + kgrp * 8;
    const ushort* a2p = xb + (size_t)(mt2 * 16 + c) * DD + kgrp * 8;
    const ushort* a3p = xb + (size_t)(r3  * 16 + c) * DD + kgrp * 8;

    f32x4 acc00, acc01, acc10, acc11, acc20, acc21, acc30, acc31;
    for (int r = 0; r < 4; ++r) {
        acc00[r]=0.f; acc01[r]=0.f; acc10[r]=0.f; acc11[r]=0.f;
        acc20[r]=0.f; acc21[r]=0.f; acc30[r]=0.f; acc31[r]=0.f;
    }

    short8 e0,e1,e2,e3,e4,e5,e6,e7;   // A set E (tile j: e(2j)=chunk0, e(2j+1)=chunk1)
    short8 o0,o1,o2,o3,o4,o5,o6,o7;   // A set O
    f32x4 u0,u1,u2,u3,u4,u5,u6,u7;    // W fp32: col0 {0,16,128,144}, col1 {...}

#define ISSUEW { \
        GL(u0, wp0, 0); GL(u1, wp0, 16); GL(u2, wp0, 128); GL(u3, wp0, 144); \
        GL(u4, wp1, 0); GL(u5, wp1, 16); GL(u6, wp1, 128); GL(u7, wp1, 144); \
        wp0 += 64; wp1 += 64; }
#define ISSUEA(S) { \
        GL(S##0, a0p, 0); GL(S##1, a0p, 64); \
        GL(S##2, a1p, 0); GL(S##3, a1p, 64); \
        GL(S##4, a2p, 0); GL(S##5, a2p, 64); \
        GL(S##6, a3p, 0); GL(S##7, a3p, 64); \
        a0p += 64; a1p += 64; a2p += 64; a3p += 64; }
#define MF(AU) { \
        acc00 = __builtin_amdgcn_mfma_f32_16x16x32_bf16(AU##0, b00, acc00, 0, 0, 0); \
        acc01 = __builtin_amdgcn_mfma_f32_16x16x32_bf16(AU##0, b10, acc01, 0, 0, 0); \
        acc00 = __builtin_amdgcn_mfma_f32_16x16x32_bf16(AU##1, b01, acc00, 0, 0, 0); \
        acc01 = __builtin_amdgcn_mfma_f32_16x16x32_bf16(AU##1, b11, acc01, 0, 0, 0); \
        acc10 = __builtin_amdgcn_mfma_f32_16x16x32_bf16(AU##2, b00, acc10, 0, 0, 0); \
        acc11 = __builtin_amdgcn_mfma_f32_16x16x32_bf16(AU##2, b10, acc11, 0, 0, 0); \
        acc10 = __builtin_amdgcn_mfma_f32_16x16x32_bf16(AU##3, b01, acc10, 0, 0, 0); \
        acc11 = __builtin_amdgcn_mfma_f32_16x16x32_bf16(AU##3, b11, acc11, 0, 0, 0); \
        acc20 = __builtin_amdgcn_mfma_f32_16x16x32_bf16(AU##4, b00, acc20, 0, 0, 0); \
        acc21 = __builtin_amdgcn_mfma_f32_16x16x32_bf16(AU##4, b10, acc21, 0, 0, 0); \
        acc20 = __builtin_amdgcn_mfma_f32_16x16x32_bf16(AU##5, b01, acc20, 0, 0, 0); \
        acc21 = __builtin_amdgcn_mfma_f32_16x16x32_bf16(AU##5, b11, acc21, 0, 0, 0); \
        acc30 = __builtin_amdgcn_mfma_f32_16x16x32_bf16(AU##6, b00, acc30, 0, 0, 0); \
        acc31 = __builtin_amdgcn_mfma_f32_16x16x32_bf16(AU##6, b10, acc31, 0, 0, 0); \
        acc30 = __builtin_amdgcn_mfma_f32_16x16x32_bf16(AU##7, b01, acc30, 0, 0, 0); \
        acc31 = __builtin_amdgcn_mfma_f32_16x16x32_bf16(AU##7, b11, acc31, 0, 0, 0); }
#define PHASE(AU, AO) { \
        WAITV(8); SB; \
        short8 b00 = pack8f(u0, u1), b01 = pack8f(u2, u3); \
        short8 b10 = pack8f(u4, u5), b11 = pack8f(u6, u7); \
        SB; \
        ISSUEW; ISSUEA(AO); SB; \
        WAITV(16); SB; \
        MF(AU); SB; }
#define PHASEF(AU) { \
        WAITV(8); SB; \
        short8 b00 = pack8f(u0, u1), b01 = pack8f(u2, u3); \
        short8 b10 = pack8f(u4, u5), b11 = pack8f(u6, u7); \
        SB; \
        WAITV(0); SB; \
        MF(AU); SB; }

    // prologue: queue = [W(0):8, A(0):8]; ptrs -> k=64
    ISSUEW; ISSUEA(e); SB;

    #pragma unroll 1
    for (int it = 0; it < 63; ++it) {   // phases 0..125
        PHASE(e, o);
        PHASE(o, e);
    }
    PHASE(e, o);                         // phase 126 (issues k=8128 -> o)
    PHASEF(o);                           // phase 127 (no issue)

#undef PHASE
#undef PHASEF
#undef MF
#undef ISSUEA
#undef ISSUEW

    // ---------------- epilogue: direct stores (no partials)
    const float b0v = bias[ncol0];
    const float b1v = bias[ncol1];
#define STORE_TILE(MTV, A0, A1) { \
        if ((MTV) < MT) { \
            if (mat < 2) { \
                ushort* outb = (mat == 0) ? qb : kb; \
                _Pragma("unroll") for (int r = 0; r < 4; ++r) { \
                    int row = (MTV) * 16 + kgrp * 4 + r; \
                    outb[(size_t)row * DD + ncol0] = f2bf(A0[r] + b0v); \
                    outb[(size_t)row * DD + ncol1] = f2bf(A1[r] + b1v); \
                } \
            } else { \
                _Pragma("unroll") for (int r = 0; r < 4; ++r) { \
                    int row = (MTV) * 16 + kgrp * 4 + r; \
                    vt[(size_t)ncol0 * KPV + row] = f2bf(A0[r] + b0v); \
                    vt[(size_t)ncol1 * KPV + row] = f2bf(A1[r] + b1v); \
                } \
            } \
        } }
    STORE_TILE(mt0, acc00, acc01);
    STORE_TILE(mt1, acc10, acc11);
    STORE_TILE(mt2, acc20, acc21);
    STORE_TILE(mt3, acc30, acc31);
#undef STORE_TILE
}

// ---------------- kernel 4: s = q @ k^T  (f32 [208][208]); grid (13,13), 4-wave K-split
__global__ __launch_bounds__(256) void sgemm(const ushort* __restrict__ qb, const ushort* __restrict__ kb,
                                             float* __restrict__ sbuf) {
    const int bm = blockIdx.y, bn = blockIdx.x;
    const int lane  = threadIdx.x & 63;
    const int wave  = threadIdx.x >> 6;
    const int col16 = lane & 15, kgrp = lane >> 4;
    const ushort* ap = qb + (size_t)(bm * 16 + col16) * DD + kgrp * 8;
    const ushort* bp = kb + (size_t)(bn * 16 + col16) * DD + kgrp * 8;
    f32x4 acc;
    for (int r = 0; r < 4; ++r) acc[r] = 0.f;
    const int kend = (wave + 1) * 2048;
    for (int k0 = wave * 2048; k0 < kend; k0 += 32) {
        short8 a = *reinterpret_cast<const short8*>(ap + k0);
        short8 b = *reinterpret_cast<const short8*>(bp + k0);
        acc = __builtin_amdgcn_mfma_f32_16x16x32_bf16(a, b, acc, 0, 0, 0);
    }
    __shared__ f32x4 red[4][64];
    red[wave][lane] = acc;
    __syncthreads();
    if (wave == 0) {
        f32x4 s = red[0][lane];
        for (int j = 1; j < 4; ++j) { f32x4 o = red[j][lane]; for (int r = 0; r < 4; ++r) s[r] += o[r]; }
        for (int r = 0; r < 4; ++r)
            sbuf[(size_t)(bm * 16 + kgrp * 4 + r) * MPAD + bn * 16 + col16] = s[r];
    }
}

// ---------------- kernel 5: per-row mean/var(ddof=1) -> sin -> softmax -> P bf16 [208][256] (pads 0)
__global__ __launch_bounds__(256) void rownorm(const float* __restrict__ sbuf, ushort* __restrict__ pb) {
    const int row = blockIdx.x;
    const int t = threadIdx.x;
    if (row >= NROW) { pb[(size_t)row * KPV + t] = 0; return; }
    __shared__ float part[4];
    const int lane = t & 63, wave = t >> 6;
    float x = (t < NROW) ? sbuf[(size_t)row * MPAD + t] : 0.f;

    float s = x;
    for (int m = 32; m; m >>= 1) s += __shfl_xor(s, m, 64);
    if (lane == 0) part[wave] = s;
    __syncthreads();
    float mean = (part[0] + part[1] + part[2] + part[3]) * (1.f / 200.f);

    float d = (t < NROW) ? (x - mean) : 0.f;
    float s2 = d * d;
    for (int m = 32; m; m >>= 1) s2 += __shfl_xor(s2, m, 64);
    __syncthreads();
    if (lane == 0) part[wave] = s2;
    __syncthreads();
    float var = (part[0] + part[1] + part[2] + part[3]) * (1.f / 199.f);

    float inv = 1.f / sqrtf(var + EPSV);
    float y = sinf(d * inv);
    const float inv_cc = 1.f / 90.50966799187809f;   // 1/sqrt(8192)
    float e = (t < NROW) ? expf(y * inv_cc) : 0.f;

    float se = e;
    for (int m = 32; m; m >>= 1) se += __shfl_xor(se, m, 64);
    __syncthreads();
    if (lane == 0) part[wave] = se;
    __syncthreads();
    float tot = part[0] + part[1] + part[2] + part[3];
    pb[(size_t)row * KPV + t] = (t < NROW) ? f2bf(e / tot) : (ushort)0;
}

// ---------------- kernel 6: out = P @ V  via out[m][n] = sum_k P[m][k] * vt[n][k]
__global__ __launch_bounds__(256) void pv_gemm(const ushort* __restrict__ pb, const ushort* __restrict__ vt,
                                               float* __restrict__ out) {
    const int lane  = threadIdx.x & 63;
    const int wave  = threadIdx.x >> 6;
    const int col16 = lane & 15, kgrp = lane >> 4;
    const int ncol  = blockIdx.x * 64 + wave * 16 + col16;
    const ushort* ap = pb + (size_t)col16 * KPV + kgrp * 8;
    const ushort* bp = vt + (size_t)ncol  * KPV + kgrp * 8;
    f32x4 acc[MT];
    for (int m = 0; m < MT; ++m)
        for (int r = 0; r < 4; ++r) acc[m][r] = 0.f;
    for (int k0 = 0; k0 < KPV; k0 += 32) {
        short8 b = *reinterpret_cast<const short8*>(bp + k0);
        #pragma unroll
        for (int m = 0; m < MT; ++m) {
            short8 a = *reinterpret_cast<const short8*>(ap + (size_t)m * 16 * KPV + k0);
            acc[m] = __builtin_amdgcn_mfma_f32_16x16x32_bf16(a, b, acc[m], 0, 0, 0);
        }
    }
    for (int m = 0; m < MT; ++m)
        for (int r = 0; r < 4; ++r) {
            int row = m * 16 + kgrp * 4 + r;
            if (row < NROW) out[(size_t)row * DD + ncol] = acc[m][r];
        }
}

extern "C" void kernel_launch(void* const* d_in, const int* in_sizes, int n_in,
                              void* d_out, int out_size, void* d_ws, size_t ws_size,
                              hipStream_t stream) {
    const float* x  = (const float*)d_in[0];
    const float* Wq = (const float*)d_in[1];
    const float* bq = (const float*)d_in[2];
    const float* Wk = (const float*)d_in[3];
    const float* bk = (const float*)d_in[4];
    const float* Wv = (const float*)d_in[5];
    const float* bv = (const float*)d_in[6];
    float* out = (float*)d_out;

    char* ws = (char*)d_ws;
    ushort* xb   = (ushort*)(ws);                       // 208*8192*2 = 3,407,872
    ushort* qb   = (ushort*)(ws + 3407872);             // 3,407,872
    ushort* kb   = (ushort*)(ws + 6815744);             // 3,407,872
    ushort* vt   = (ushort*)(ws + 10223616);            // 8192*256*2 = 4,194,304
    float*  sbuf = (float*)(ws + 14417920);             // 208*208*4 = 173,056
    ushort* pb   = (ushort*)(ws + 14590976);            // 208*256*2 = 106,496
    // total 14,697,472 bytes

    cvt_x<<<832, 256, 0, stream>>>(x, xb);
    qkv_fr<<<768, 256, 0, stream>>>(xb, Wq, Wk, Wv, bq, bk, bv, qb, kb, vt);
    sgemm<<<dim3(13, 13), 256, 0, stream>>>(qb, kb, sbuf);
    rownorm<<<208, 256, 0, stream>>>(sbuf, pb);
    pv_gemm<<<128, 256, 0, stream>>>(pb, vt, out);
}

// Round 14
// 254.838 us; speedup vs baseline: 3.1146x; 3.1082x over previous
//
#include <hip/hip_runtime.h>
#include <hip/hip_bf16.h>
#include <cstdint>

#define DD 8192
#define NROW 200
#define MT 13          // 13 M-tiles of 16 rows = 208
#define MPAD 208
#define KPV 256        // padded K for the PV GEMM
#define EPSV 1e-5f
#define BK 64
#define ABUF_BYTES (MPAD * BK * 2)   // 26624 bytes per LDS x-buffer

using short8 = __attribute__((ext_vector_type(8))) short;
using f32x4  = __attribute__((ext_vector_type(4))) float;

__device__ __forceinline__ ushort f2bf(float f) {
    union { float f; unsigned u; } c; c.f = f;
    unsigned u = c.u;
    return (ushort)((u + 0x7FFFu + ((u >> 16) & 1u)) >> 16);  // RNE
}

__device__ __forceinline__ short8 pack8(float4 a, float4 b) {
    short8 o;
    o[0]=f2bf(a.x); o[1]=f2bf(a.y); o[2]=f2bf(a.z); o[3]=f2bf(a.w);
    o[4]=f2bf(b.x); o[5]=f2bf(b.y); o[6]=f2bf(b.z); o[7]=f2bf(b.w);
    return o;
}

// fast pack via v_cvt_pk_bf16_f32 (RNE, same semantics as f2bf)
__device__ __forceinline__ short8 pack8f(f32x4 a, f32x4 b) {
    short8 o;
    union { __hip_bfloat162 h; unsigned u; } q;
    q.h = __float22bfloat162_rn(float2{a[0], a[1]}); o[0]=(short)(q.u & 0xffff); o[1]=(short)(q.u >> 16);
    q.h = __float22bfloat162_rn(float2{a[2], a[3]}); o[2]=(short)(q.u & 0xffff); o[3]=(short)(q.u >> 16);
    q.h = __float22bfloat162_rn(float2{b[0], b[1]}); o[4]=(short)(q.u & 0xffff); o[5]=(short)(q.u >> 16);
    q.h = __float22bfloat162_rn(float2{b[2], b[3]}); o[6]=(short)(q.u & 0xffff); o[7]=(short)(q.u >> 16);
    return o;
}

// ---------------- kernel 1: x (f32 [200][8192]) -> xb (bf16 [208][8192], pad rows 0)
__global__ void cvt_x(const float* __restrict__ x, ushort* __restrict__ xb) {
    int i = (blockIdx.x * 256 + threadIdx.x) * 8;
    int row = i >> 13;
    int col = i & (DD - 1);
    short8 o;
    if (row < NROW) {
        const float4* p = reinterpret_cast<const float4*>(x + (size_t)row * DD + col);
        float4 a = p[0], b = p[1];
        o = pack8(a, b);
    } else {
        for (int j = 0; j < 8; ++j) o[j] = 0;
    }
    *reinterpret_cast<short8*>(xb + i) = o;
}

#define GL(dst, ptr, OFF) \
    asm volatile("global_load_dwordx4 %0, %1, off offset:" #OFF \
                 : "=&v"(dst) : "v"(ptr) : "memory")
#define WAITV(N) asm volatile("s_waitcnt vmcnt(" #N ")" ::: "memory")
#define SB __builtin_amdgcn_sched_barrier(0)
#define RAWBAR asm volatile("s_barrier" ::: "memory")

// ---------------- kernel 2: fused QKV GEMM — ALL 3 MATS PER BLOCK (3x less x-traffic).
// grid 256 (= colblocks of 32), block 384 (6 waves): wave = (mat = w>>1, colgroup = w&1),
// each wave: 16 cols x 13 M-tiles x full K. x k-slice [208][64] bf16 double-buffered in
// LDS via gl_lds (swizzled source), staged cooperatively (26 loads split 5/5/4/4/4/4);
// W via inline-asm GL into reg-dbuf, 1-phase slack; one counted WAITV retires exactly
// {stage(t), W(t)}. 2 raw barriers/phase. 1 block/CU, 6 waves/CU. No partials.
__global__ __launch_bounds__(384) void qkv_s6(
    const ushort* __restrict__ xb,
    const float* __restrict__ Wq, const float* __restrict__ Wk, const float* __restrict__ Wv,
    const float* __restrict__ bq, const float* __restrict__ bk, const float* __restrict__ bv,
    ushort* __restrict__ qb, ushort* __restrict__ kb, ushort* __restrict__ vt)
{
    __shared__ char L[2 * ABUF_BYTES];   // 53,248 B

    const int cb   = blockIdx.x;        // col-block (32 cols, shared by 3 mats)
    const int t    = threadIdx.x;
    const int lane = t & 63;
    const int wave = t >> 6;            // 0..5
    const int mat  = wave >> 1;         // 0..2
    const int cg   = wave & 1;          // colgroup
    const int c    = lane & 15;
    const int kgrp = lane >> 4;
    const int ncol = cb * 32 + cg * 16 + c;

    const float* W    = (mat == 0) ? Wq : (mat == 1 ? Wk : Wv);
    const float* bias = (mat == 0) ? bq : (mat == 1 ? bk : bv);
    const float* wq   = W + (size_t)ncol * DD + kgrp * 8;

    // x staging: per gl_lds, 64 lanes x 16B = 8 rows x 128B linear; swizzled global
    // source so content at (row, slot16B) holds k-slot = slot ^ (row&7).
    const ushort* sbase = xb + (size_t)(lane >> 3) * DD
                             + (size_t)(((lane & 7) ^ ((lane >> 3) & 7)) * 8);
    // 26 groups of 8 rows; wave w stages groups {w, w+6, w+12, w+18, w+24(<26)}
    // -> waves 0,1: 5 loads; waves 2-5: 4 loads.

    // ds_read a-frag (tile m, chunk j): row = m*16+c, slot = (j*4+kgrp) ^ (c&7)
    const int b0off = c * 128 + ((kgrp ^ (c & 7)) * 16);
    const int b1off = b0off ^ 64;

    f32x4 acc[MT];
    #pragma unroll
    for (int m = 0; m < MT; ++m)
        for (int r = 0; r < 4; ++r) acc[m][r] = 0.f;

    f32x4 uA0, uA1, uA2, uA3, uB0, uB1, uB2, uB3;

#define STAGE(B, KK) { _Pragma("unroll") for (int j = 0; j < 5; ++j) { \
        int g = wave + 6 * j; \
        if (g < 26) { \
            __builtin_amdgcn_global_load_lds( \
                (const __attribute__((address_space(1))) void*)(sbase + (KK) + (size_t)g * 8 * DD), \
                (__attribute__((address_space(3))) void*)(L + (B) + g * 1024), \
                16, 0, 0); } } }

#define COMPUTE(RB, bb0, bb1) { _Pragma("unroll") for (int m = 0; m < MT; ++m) { \
        short8 a0 = *reinterpret_cast<const short8*>(L + (RB) + m * 2048 + b0off); \
        acc[m] = __builtin_amdgcn_mfma_f32_16x16x32_bf16(a0, bb0, acc[m], 0, 0, 0); \
        short8 a1 = *reinterpret_cast<const short8*>(L + (RB) + m * 2048 + b1off); \
        acc[m] = __builtin_amdgcn_mfma_f32_16x16x32_bf16(a1, bb1, acc[m], 0, 0, 0); } }

// phase: stage(t+1) -> other buf; WAITV retires {stage(t), W(t)}; pack W(t);
// issue W(t+2) into freed regs; barrier; MFMA from buf(t); barrier.
#define PHASE(RB, UC) { \
        STAGE((RB) ^ ABUF_BYTES, kn); \
        kn = (kn + BK) & (DD - 1); \
        if (wave < 2) { WAITV(9); } else { WAITV(8); } \
        SB; \
        short8 bb0 = pack8f(UC##0, UC##1); \
        short8 bb1 = pack8f(UC##2, UC##3); \
        GL(UC##0, wq + k2, 0); \
        GL(UC##1, wq + k2, 16); \
        GL(UC##2, wq + k2, 128); \
        GL(UC##3, wq + k2, 144); \
        k2 = (k2 + BK) & (DD - 1); \
        RAWBAR; \
        COMPUTE(RB, bb0, bb1); \
        asm volatile("s_waitcnt lgkmcnt(0)" ::: "memory"); \
        RAWBAR; }

    // ---------------- prologue: stage(0) -> buf0; W(0) -> uA; W(1) -> uB
    int kn = BK;     // next stage k
    int k2 = 2 * BK; // next W k
    STAGE(0, 0);
    GL(uA0, wq, 0);  GL(uA1, wq, 16);  GL(uA2, wq, 128);  GL(uA3, wq, 144);
    GL(uB0, wq + BK, 0); GL(uB1, wq + BK, 16); GL(uB2, wq + BK, 128); GL(uB3, wq + BK, 144);
    // queue: [stage0:sw, W0:4, W1:4]

    #pragma unroll 1
    for (int it = 0; it < DD / (2 * BK); ++it) {
        PHASE(0, uA);            // even: read buf0, consume W(even)
        PHASE(ABUF_BYTES, uB);   // odd:  read buf1, consume W(odd)
    }
#undef PHASE
#undef COMPUTE
#undef STAGE

    // ---------------- epilogue: direct stores (no partials)
    const float bv0 = bias[ncol];
    if (mat < 2) {
        ushort* outb = (mat == 0) ? qb : kb;
        #pragma unroll
        for (int m = 0; m < MT; ++m)
            for (int r = 0; r < 4; ++r) {
                int row = m * 16 + kgrp * 4 + r;   // C/D: col=lane&15, row=(lane>>4)*4+r
                outb[(size_t)row * DD + ncol] = f2bf(acc[m][r] + bv0);
            }
    } else {
        // write V directly transposed: vt[n][k] = v[k][n], bf16
        #pragma unroll
        for (int m = 0; m < MT; ++m)
            for (int r = 0; r < 4; ++r) {
                int row = m * 16 + kgrp * 4 + r;
                vt[(size_t)ncol * KPV + row] = f2bf(acc[m][r] + bv0);
            }
    }
}

// ---------------- kernel 4: s = q @ k^T  (f32 [208][208]); grid (13,13), 4-wave K-split
__global__ __launch_bounds__(256) void sgemm(const ushort* __restrict__ qb, const ushort* __restrict__ kb,
                                             float* __restrict__ sbuf) {
    const int bm = blockIdx.y, bn = blockIdx.x;
    const int lane  = threadIdx.x & 63;
    const int wave  = threadIdx.x >> 6;
    const int col16 = lane & 15, kgrp = lane >> 4;
    const ushort* ap = qb + (size_t)(bm * 16 + col16) * DD + kgrp * 8;
    const ushort* bp = kb + (size_t)(bn * 16 + col16) * DD + kgrp * 8;
    f32x4 acc;
    for (int r = 0; r < 4; ++r) acc[r] = 0.f;
    const int kend = (wave + 1) * 2048;
    for (int k0 = wave * 2048; k0 < kend; k0 += 32) {
        short8 a = *reinterpret_cast<const short8*>(ap + k0);
        short8 b = *reinterpret_cast<const short8*>(bp + k0);
        acc = __builtin_amdgcn_mfma_f32_16x16x32_bf16(a, b, acc, 0, 0, 0);
    }
    __shared__ f32x4 red[4][64];
    red[wave][lane] = acc;
    __syncthreads();
    if (wave == 0) {
        f32x4 s = red[0][lane];
        for (int j = 1; j < 4; ++j) { f32x4 o = red[j][lane]; for (int r = 0; r < 4; ++r) s[r] += o[r]; }
        for (int r = 0; r < 4; ++r)
            sbuf[(size_t)(bm * 16 + kgrp * 4 + r) * MPAD + bn * 16 + col16] = s[r];
    }
}

// ---------------- kernel 5: per-row mean/var(ddof=1) -> sin -> softmax -> P bf16 [208][256] (pads 0)
__global__ __launch_bounds__(256) void rownorm(const float* __restrict__ sbuf, ushort* __restrict__ pb) {
    const int row = blockIdx.x;
    const int t = threadIdx.x;
    if (row >= NROW) { pb[(size_t)row * KPV + t] = 0; return; }
    __shared__ float part[4];
    const int lane = t & 63, wave = t >> 6;
    float x = (t < NROW) ? sbuf[(size_t)row * MPAD + t] : 0.f;

    float s = x;
    for (int m = 32; m; m >>= 1) s += __shfl_xor(s, m, 64);
    if (lane == 0) part[wave] = s;
    __syncthreads();
    float mean = (part[0] + part[1] + part[2] + part[3]) * (1.f / 200.f);

    float d = (t < NROW) ? (x - mean) : 0.f;
    float s2 = d * d;
    for (int m = 32; m; m >>= 1) s2 += __shfl_xor(s2, m, 64);
    __syncthreads();
    if (lane == 0) part[wave] = s2;
    __syncthreads();
    float var = (part[0] + part[1] + part[2] + part[3]) * (1.f / 199.f);

    float inv = 1.f / sqrtf(var + EPSV);
    float y = sinf(d * inv);
    const float inv_cc = 1.f / 90.50966799187809f;   // 1/sqrt(8192)
    float e = (t < NROW) ? expf(y * inv_cc) : 0.f;

    float se = e;
    for (int m = 32; m; m >>= 1) se += __shfl_xor(se, m, 64);
    __syncthreads();
    if (lane == 0) part[wave] = se;
    __syncthreads();
    float tot = part[0] + part[1] + part[2] + part[3];
    pb[(size_t)row * KPV + t] = (t < NROW) ? f2bf(e / tot) : (ushort)0;
}

// ---------------- kernel 6: out = P @ V  via out[m][n] = sum_k P[m][k] * vt[n][k]
__global__ __launch_bounds__(256) void pv_gemm(const ushort* __restrict__ pb, const ushort* __restrict__ vt,
                                               float* __restrict__ out) {
    const int lane  = threadIdx.x & 63;
    const int wave  = threadIdx.x >> 6;
    const int col16 = lane & 15, kgrp = lane >> 4;
    const int ncol  = blockIdx.x * 64 + wave * 16 + col16;
    const ushort* ap = pb + (size_t)col16 * KPV + kgrp * 8;
    const ushort* bp = vt + (size_t)ncol  * KPV + kgrp * 8;
    f32x4 acc[MT];
    for (int m = 0; m < MT; ++m)
        for (int r = 0; r < 4; ++r) acc[m][r] = 0.f;
    for (int k0 = 0; k0 < KPV; k0 += 32) {
        short8 b = *reinterpret_cast<const short8*>(bp + k0);
        #pragma unroll
        for (int m = 0; m < MT; ++m) {
            short8 a = *reinterpret_cast<const short8*>(ap + (size_t)m * 16 * KPV + k0);
            acc[m] = __builtin_amdgcn_mfma_f32_16x16x32_bf16(a, b, acc[m], 0, 0, 0);
        }
    }
    for (int m = 0; m < MT; ++m)
        for (int r = 0; r < 4; ++r) {
            int row = m * 16 + kgrp * 4 + r;
            if (row < NROW) out[(size_t)row * DD + ncol] = acc[m][r];
        }
}

extern "C" void kernel_launch(void* const* d_in, const int* in_sizes, int n_in,
                              void* d_out, int out_size, void* d_ws, size_t ws_size,
                              hipStream_t stream) {
    const float* x  = (const float*)d_in[0];
    const float* Wq = (const float*)d_in[1];
    const float* bq = (const float*)d_in[2];
    const float* Wk = (const float*)d_in[3];
    const float* bk = (const float*)d_in[4];
    const float* Wv = (const float*)d_in[5];
    const float* bv = (const float*)d_in[6];
    float* out = (float*)d_out;

    char* ws = (char*)d_ws;
    ushort* xb   = (ushort*)(ws);                       // 208*8192*2 = 3,407,872
    ushort* qb   = (ushort*)(ws + 3407872);             // 3,407,872
    ushort* kb   = (ushort*)(ws + 6815744);             // 3,407,872
    ushort* vt   = (ushort*)(ws + 10223616);            // 8192*256*2 = 4,194,304
    float*  sbuf = (float*)(ws + 14417920);             // 208*208*4 = 173,056
    ushort* pb   = (ushort*)(ws + 14590976);            // 208*256*2 = 106,496
    // total 14,697,472 bytes

    cvt_x<<<832, 256, 0, stream>>>(x, xb);
    qkv_s6<<<256, 384, 0, stream>>>(xb, Wq, Wk, Wv, bq, bk, bv, qb, kb, vt);
    sgemm<<<dim3(13, 13), 256, 0, stream>>>(qb, kb, sbuf);
    rownorm<<<208, 256, 0, stream>>>(sbuf, pb);
    pv_gemm<<<128, 256, 0, stream>>>(pb, vt, out);
}